// Round 9
// baseline (4424.572 us; speedup 1.0000x reference)
//
#include <hip/hip_runtime.h>
#include <stdint.h>

// Problem constants
#define HID 100
#define B_TOTAL 512
#define T_IN 1000
#define NB 2
#define BLOCK 512   // 8 waves, 2 waves/EU -> 256 unified regs/wave

typedef __fp16 f16x8 __attribute__((ext_vector_type(8)));
typedef float f32x4 __attribute__((ext_vector_type(4)));

// SWAPPED ROLES: A = weight tile (m=gate col), B = h (n=batch col).
// C[row=gate,col=batch]: lane (q=lane>>4,b=lane&15) holds gates 4q..4q+3 of its
// cell in c[0..3] -> per-lane LSTM activation, no cross-lane gather.
#define MF(A_, B_, C_) __builtin_amdgcn_mfma_f32_16x16x32_f16((A_), (B_), (C_), 0, 0, 0)

__device__ __forceinline__ float sigm(float x) { return 1.0f / (1.0f + __expf(-x)); }
__device__ __forceinline__ float tanh_fast(float x) {
  float e = __expf(2.0f * x);
  return 1.0f - 2.0f / (e + 1.0f);
}

// weight element fetchers (0 in pad regions). j = ORIGINAL gate row (0..399).
__device__ __forceinline__ __fp16 w1e(const float* Whh1, const float* Wih1, int j, int k) {
  float v = 0.0f;
  if (k < 100) v = Whh1[j * 100 + k];
  else if (k == 100) v = Wih1[j];
  return (__fp16)v;
}
__device__ __forceinline__ __fp16 w2e(const float* Wih2, int j, int k) {
  float v = 0.0f; if (k < 100) v = Wih2[j * 100 + k]; return (__fp16)v;
}
__device__ __forceinline__ __fp16 w3e(const float* Whh2, int j, int k) {
  float v = 0.0f; if (k < 100) v = Whh2[j * 100 + k]; return (__fp16)v;
}

// A-operand frag for (permuted col J, K-tile KT): elem e of lane = W[J][KT*32+kg*8+e]
// (same index structure as R5's verified MKB; A layout mirrors B layout)
#define MKW1(J, KT) (f16x8){ \
  w1e(Whh1,Wih1,(J),(KT)*32+kg*8+0), w1e(Whh1,Wih1,(J),(KT)*32+kg*8+1), \
  w1e(Whh1,Wih1,(J),(KT)*32+kg*8+2), w1e(Whh1,Wih1,(J),(KT)*32+kg*8+3), \
  w1e(Whh1,Wih1,(J),(KT)*32+kg*8+4), w1e(Whh1,Wih1,(J),(KT)*32+kg*8+5), \
  w1e(Whh1,Wih1,(J),(KT)*32+kg*8+6), w1e(Whh1,Wih1,(J),(KT)*32+kg*8+7) }
#define MKW2(J, KT) (f16x8){ \
  w2e(Wih2,(J),(KT)*32+kg*8+0), w2e(Wih2,(J),(KT)*32+kg*8+1), \
  w2e(Wih2,(J),(KT)*32+kg*8+2), w2e(Wih2,(J),(KT)*32+kg*8+3), \
  w2e(Wih2,(J),(KT)*32+kg*8+4), w2e(Wih2,(J),(KT)*32+kg*8+5), \
  w2e(Wih2,(J),(KT)*32+kg*8+6), w2e(Wih2,(J),(KT)*32+kg*8+7) }
#define MKW3(J, KT) (f16x8){ \
  w3e(Whh2,(J),(KT)*32+kg*8+0), w3e(Whh2,(J),(KT)*32+kg*8+1), \
  w3e(Whh2,(J),(KT)*32+kg*8+2), w3e(Whh2,(J),(KT)*32+kg*8+3), \
  w3e(Whh2,(J),(KT)*32+kg*8+4), w3e(Whh2,(J),(KT)*32+kg*8+5), \
  w3e(Whh2,(J),(KT)*32+kg*8+6), w3e(Whh2,(J),(KT)*32+kg*8+7) }

__global__ __launch_bounds__(BLOCK, 2) void lstm2_mfma2(
    const float* __restrict__ input,  // [512,1000]
    const float* __restrict__ Wih1,   // [400,1]
    const float* __restrict__ Whh1,   // [400,100]
    const float* __restrict__ bih1,
    const float* __restrict__ bhh1,
    const float* __restrict__ Wih2,   // [400,100]
    const float* __restrict__ Whh2,   // [400,100]
    const float* __restrict__ bih2,
    const float* __restrict__ bhh2,
    const float* __restrict__ Wlin,   // [1,100]
    const float* __restrict__ blin,   // [1]
    const int* __restrict__ futp,
    float* __restrict__ out)          // [512, 1000+future]
{
  // compact h buffers, double-buffered by t-parity. Per K-tile: 80 f16 =
  // [col0 k0..31 | col1 k0..31 | zero chunk (16) ]. k=100 slot = x.
  __shared__ __align__(16) __fp16 Hb1[2][320];   // h1 (+x at k100), 4 K-tiles
  __shared__ __align__(16) __fp16 Hb2[2][320];   // h2, 4 K-tiles
  __shared__ __align__(16) __fp16 BW1[4 * 512];  // tile-24 weight frags (wave 0)
  __shared__ __align__(16) __fp16 BW2[4 * 512];
  __shared__ __align__(16) __fp16 BW3[4 * 512];
  __shared__ float xrow[NB][T_IN];               // staged inputs (8 KB)
  __shared__ __align__(16) float ybuf[NB][104];  // h2(t) f32 (pads 0)
  __shared__ __align__(16) float wls[104];       // Wlin staged (pads 0)

  const int tid = threadIdx.x;
  const int lane = tid & 63;
  const int wv = tid >> 6;
  const int q = lane >> 4;    // K-group for frags; cell-local; C row-quad
  const int bb = lane & 15;   // batch col (real 0,1); weight-col selector
  const int kg = q;
  const int b0 = blockIdx.x * NB;
  const int F = futp[0];
  const int TT = T_IN + F;

  // ---------------- init ----------------
  for (int i = tid; i < NB * T_IN; i += BLOCK) {
    int b = i / T_IN, t = i % T_IN;
    xrow[b][t] = input[(size_t)(b0 + b) * T_IN + t];
  }
  if (tid < 320) { ((uint32_t*)Hb1)[tid] = 0u; ((uint32_t*)Hb2)[tid] = 0u; }
  if (tid < 104) wls[tid] = (tid < HID) ? Wlin[tid] : 0.0f;
  if (tid < 208) ((float*)ybuf)[tid] = 0.0f;
  if (tid < 2)   // x(0) -> Hb1[0] k=100 (cidx(100,b)=240+b*32+4); read from global
    Hb1[0][240 + tid * 32 + 4] = (__fp16)input[(size_t)(b0 + tid) * T_IN + 0];

  // ---------------- register weight frags: tiles T0,T1,T2 per wave ----------------
  // permuted col n=4c+g <-> orig row j=g*100+c ; ja = (bb&3)*100 + 4*T + (bb>>2)
  const int T0 = wv, T1 = 8 + wv, T2 = 16 + wv;
  const int jA = (bb & 3) * 100 + 4 * T0 + (bb >> 2);
  const int jB = (bb & 3) * 100 + 4 * T1 + (bb >> 2);
  const int jC = (bb & 3) * 100 + 4 * T2 + (bb >> 2);
  f16x8 W1a0=MKW1(jA,0), W1a1=MKW1(jA,1), W1a2=MKW1(jA,2), W1a3=MKW1(jA,3);
  f16x8 W1b0=MKW1(jB,0), W1b1=MKW1(jB,1), W1b2=MKW1(jB,2), W1b3=MKW1(jB,3);
  f16x8 W1c0=MKW1(jC,0), W1c1=MKW1(jC,1), W1c2=MKW1(jC,2), W1c3=MKW1(jC,3);
  f16x8 W2a0=MKW2(jA,0), W2a1=MKW2(jA,1), W2a2=MKW2(jA,2), W2a3=MKW2(jA,3);
  f16x8 W2b0=MKW2(jB,0), W2b1=MKW2(jB,1), W2b2=MKW2(jB,2), W2b3=MKW2(jB,3);
  f16x8 W2c0=MKW2(jC,0), W2c1=MKW2(jC,1), W2c2=MKW2(jC,2), W2c3=MKW2(jC,3);
  f16x8 W3a0=MKW3(jA,0), W3a1=MKW3(jA,1), W3a2=MKW3(jA,2), W3a3=MKW3(jA,3);
  f16x8 W3b0=MKW3(jB,0), W3b1=MKW3(jB,1), W3b2=MKW3(jB,2), W3b3=MKW3(jB,3);
  f16x8 W3c0=MKW3(jC,0), W3c1=MKW3(jC,1), W3c2=MKW3(jC,2), W3c3=MKW3(jC,3);

  // tile 24 (cells 96..99) frags -> LDS; tids 0..63 emulate wave-0 lanes
  if (tid < 64) {
    int j24 = ((tid & 15) & 3) * 100 + 96 + ((tid & 15) >> 2);
    f16x8* V1 = (f16x8*)BW1; f16x8* V2 = (f16x8*)BW2; f16x8* V3 = (f16x8*)BW3;
    V1[0*64+tid]=MKW1(j24,0); V1[1*64+tid]=MKW1(j24,1); V1[2*64+tid]=MKW1(j24,2); V1[3*64+tid]=MKW1(j24,3);
    V2[0*64+tid]=MKW2(j24,0); V2[1*64+tid]=MKW2(j24,1); V2[2*64+tid]=MKW2(j24,2); V2[3*64+tid]=MKW2(j24,3);
    V3[0*64+tid]=MKW3(j24,0); V3[1*64+tid]=MKW3(j24,1); V3[2*64+tid]=MKW3(j24,2); V3[3*64+tid]=MKW3(j24,3);
  }

  // ---------------- per-lane biases & cell state (cell = 4T+q) ----------------
  const int cA = 4 * T0 + q, cB = 4 * T1 + q, cC = 4 * T2 + q, cD = 96 + q;
  float i1a=bih1[cA]+bhh1[cA], f1a=bih1[100+cA]+bhh1[100+cA], g1a=bih1[200+cA]+bhh1[200+cA], o1a=bih1[300+cA]+bhh1[300+cA];
  float i1b=bih1[cB]+bhh1[cB], f1b=bih1[100+cB]+bhh1[100+cB], g1b=bih1[200+cB]+bhh1[200+cB], o1b=bih1[300+cB]+bhh1[300+cB];
  float i1c=bih1[cC]+bhh1[cC], f1c=bih1[100+cC]+bhh1[100+cC], g1c=bih1[200+cC]+bhh1[200+cC], o1c=bih1[300+cC]+bhh1[300+cC];
  float i2a=bih2[cA]+bhh2[cA], f2a=bih2[100+cA]+bhh2[100+cA], g2a=bih2[200+cA]+bhh2[200+cA], o2a=bih2[300+cA]+bhh2[300+cA];
  float i2b=bih2[cB]+bhh2[cB], f2b=bih2[100+cB]+bhh2[100+cB], g2b=bih2[200+cB]+bhh2[200+cB], o2b=bih2[300+cB]+bhh2[300+cB];
  float i2c=bih2[cC]+bhh2[cC], f2c=bih2[100+cC]+bhh2[100+cC], g2c=bih2[200+cC]+bhh2[200+cC], o2c=bih2[300+cC]+bhh2[300+cC];
  float i1d=0,f1d=0,g1d=0,o1d=0,i2d=0,f2d=0,g2d=0,o2d=0;
  if (wv == 0) {
    i1d=bih1[cD]+bhh1[cD]; f1d=bih1[100+cD]+bhh1[100+cD]; g1d=bih1[200+cD]+bhh1[200+cD]; o1d=bih1[300+cD]+bhh1[300+cD];
    i2d=bih2[cD]+bhh2[cD]; f2d=bih2[100+cD]+bhh2[100+cD]; g2d=bih2[200+cD]+bhh2[200+cD]; o2d=bih2[300+cD]+bhh2[300+cD];
  }
  float s1a=0,s1b=0,s1c=0,s1d=0, s2a=0,s2b=0,s2c=0,s2d=0;  // cell states

  const int roff = (bb < 2) ? bb * 32 + q * 8 : 64;  // compact-frag read offset
  const float blin0 = blin[0];

  __syncthreads();

#define LDH(BASE, T) (*(const f16x8*)&(BASE)[(T) * 80 + roff])

#define YCOMP(Y0_, Y1_) { \
    float acc = 0.0f; int sl = lane & 31; \
    if (sl < 26) { float4 hv = ((const float4*)ybuf[lane >> 5])[sl]; \
      float4 wl4 = ((const float4*)wls)[sl]; \
      acc = hv.x*wl4.x + hv.y*wl4.y + hv.z*wl4.z + hv.w*wl4.w; } \
    acc += __shfl_down(acc, 16, 32); acc += __shfl_down(acc, 8, 32); \
    acc += __shfl_down(acc, 4, 32);  acc += __shfl_down(acc, 2, 32); \
    acc += __shfl_down(acc, 1, 32); \
    Y0_ = __shfl(acc, 0, 64) + blin0; Y1_ = __shfl(acc, 32, 64) + blin0; }

#define ACT1(CF, BI, BF, BG, BO, ST, CI) { \
    float gi = CF[0]+(BI), gf = CF[1]+(BF), gg = CF[2]+(BG), go = CF[3]+(BO); \
    ST = sigm(gf)*(ST) + sigm(gi)*tanh_fast(gg); \
    float hv = sigm(go)*tanh_fast(ST); \
    if (bb < 2) H1w[((CI) >> 5) * 80 + bb * 32 + ((CI) & 31)] = (__fp16)hv; }

#define ACT2(CF, BI, BF, BG, BO, ST, CI) { \
    float gi = CF[0]+(BI), gf = CF[1]+(BF), gg = CF[2]+(BG), go = CF[3]+(BO); \
    ST = sigm(gf)*(ST) + sigm(gi)*tanh_fast(gg); \
    float hv = sigm(go)*tanh_fast(ST); \
    if (bb < 2) { H2w[((CI) >> 5) * 80 + bb * 32 + ((CI) & 31)] = (__fp16)hv; \
                  ybuf[bb][CI] = hv; } }

#define CH4(C_, P0, P1, P2, P3, F0, F1, F2, F3) { \
    C_ = MF(P0, F0, C_); C_ = MF(P1, F1, C_); C_ = MF(P2, F2, C_); C_ = MF(P3, F3, C_); }

  const f16x8* V1 = (const f16x8*)BW1;
  const f16x8* V2 = (const f16x8*)BW2;
  const f16x8* V3 = (const f16x8*)BW3;
  const f32x4 Z = {0.f, 0.f, 0.f, 0.f};

  // ================= teacher-forced: 2 barriers/step =================
  for (int t = 0; t < T_IN; t++) {
    const __fp16* H1r = Hb1[t & 1];
    const __fp16* H2r = Hb2[t & 1];
    __fp16* H1w = Hb1[(t + 1) & 1];
    __fp16* H2w = Hb2[(t + 1) & 1];

    // ---- phase A: G1 = W1*[h1(t-1);x(t)]  and  P2 = W3*h2(t-1) (stays in regs)
    f16x8 x0 = LDH(H1r, 0), x1 = LDH(H1r, 1), x2 = LDH(H1r, 2), x3 = LDH(H1r, 3);
    f16x8 z0 = LDH(H2r, 0), z1 = LDH(H2r, 1), z2 = LDH(H2r, 2), z3 = LDH(H2r, 3);
    f32x4 gA = Z, gB = Z, gC = Z, pA = Z, pB = Z, pC = Z, g24 = Z, p24 = Z;
    CH4(gA, W1a0, W1a1, W1a2, W1a3, x0, x1, x2, x3)
    CH4(gB, W1b0, W1b1, W1b2, W1b3, x0, x1, x2, x3)
    CH4(gC, W1c0, W1c1, W1c2, W1c3, x0, x1, x2, x3)
    CH4(pA, W3a0, W3a1, W3a2, W3a3, z0, z1, z2, z3)
    CH4(pB, W3b0, W3b1, W3b2, W3b3, z0, z1, z2, z3)
    CH4(pC, W3c0, W3c1, W3c2, W3c3, z0, z1, z2, z3)
    if (wv == 0) {
      CH4(g24, V1[lane], V1[64+lane], V1[128+lane], V1[192+lane], x0, x1, x2, x3)
      CH4(p24, V3[lane], V3[64+lane], V3[128+lane], V3[192+lane], z0, z1, z2, z3)
    }
    if (wv == 7 && t > 0) {   // y(t-1) off critical path (ybuf stable until M)
      float y0, y1; YCOMP(y0, y1)
      if (lane == 0)  out[(size_t)b0 * TT + (t - 1)] = y0;
      if (lane == 32) out[(size_t)(b0 + 1) * TT + (t - 1)] = y1;
    }
    ACT1(gA, i1a, f1a, g1a, o1a, s1a, cA)
    ACT1(gB, i1b, f1b, g1b, o1b, s1b, cB)
    ACT1(gC, i1c, f1c, g1c, o1c, s1c, cC)
    if (wv == 0) ACT1(g24, i1d, f1d, g1d, o1d, s1d, cD)
    if (tid < 2 && t + 1 < T_IN)    // x(t+1) -> next-parity buffer (W2 ignores k100)
      H1w[240 + tid * 32 + 4] = (__fp16)xrow[tid][t + 1];
    __syncthreads();  // M: h1(t) visible

    // ---- phase B: G2 = P2 + W2*h1(t)
    f16x8 n0 = LDH(H1w, 0), n1 = LDH(H1w, 1), n2 = LDH(H1w, 2), n3 = LDH(H1w, 3);
    f32x4 dA = pA, dB = pB, dC = pC;
    CH4(dA, W2a0, W2a1, W2a2, W2a3, n0, n1, n2, n3)
    CH4(dB, W2b0, W2b1, W2b2, W2b3, n0, n1, n2, n3)
    CH4(dC, W2c0, W2c1, W2c2, W2c3, n0, n1, n2, n3)
    ACT2(dA, i2a, f2a, g2a, o2a, s2a, cA)
    ACT2(dB, i2b, f2b, g2b, o2b, s2b, cB)
    ACT2(dC, i2c, f2c, g2c, o2c, s2c, cC)
    if (wv == 0) {
      f32x4 d24 = p24;
      CH4(d24, V2[lane], V2[64+lane], V2[128+lane], V2[192+lane], n0, n1, n2, n3)
      ACT2(d24, i2d, f2d, g2d, o2d, s2d, cD)
    }
    __syncthreads();  // S: h2(t), ybuf(t) visible
  }

  // ================= autoregressive: 2 barriers/step =================
  for (int t = T_IN; t < TT; t++) {
    const __fp16* H1r = Hb1[t & 1];
    const __fp16* H2r = Hb2[t & 1];
    __fp16* H1w = Hb1[(t + 1) & 1];
    __fp16* H2w = Hb2[(t + 1) & 1];

    // all waves compute y(t-1) redundantly (no barrier needed for feedback)
    float y0, y1; YCOMP(y0, y1)
    if (wv == 7) {
      if (lane == 0)  out[(size_t)b0 * TT + (t - 1)] = y0;
      if (lane == 32) out[(size_t)(b0 + 1) * TT + (t - 1)] = y1;
    }
    f16x8 x0 = LDH(H1r, 0), x1 = LDH(H1r, 1), x2 = LDH(H1r, 2), x3 = LDH(H1r, 3);
    if (lane < 2) x3[4] = (__fp16)((lane == 0) ? y0 : y1);  // poke x(t)=y(t-1), k=100
    f16x8 z0 = LDH(H2r, 0), z1 = LDH(H2r, 1), z2 = LDH(H2r, 2), z3 = LDH(H2r, 3);
    f32x4 gA = Z, gB = Z, gC = Z, pA = Z, pB = Z, pC = Z, g24 = Z, p24 = Z;
    CH4(gA, W1a0, W1a1, W1a2, W1a3, x0, x1, x2, x3)
    CH4(gB, W1b0, W1b1, W1b2, W1b3, x0, x1, x2, x3)
    CH4(gC, W1c0, W1c1, W1c2, W1c3, x0, x1, x2, x3)
    CH4(pA, W3a0, W3a1, W3a2, W3a3, z0, z1, z2, z3)
    CH4(pB, W3b0, W3b1, W3b2, W3b3, z0, z1, z2, z3)
    CH4(pC, W3c0, W3c1, W3c2, W3c3, z0, z1, z2, z3)
    if (wv == 0) {
      CH4(g24, V1[lane], V1[64+lane], V1[128+lane], V1[192+lane], x0, x1, x2, x3)
      CH4(p24, V3[lane], V3[64+lane], V3[128+lane], V3[192+lane], z0, z1, z2, z3)
    }
    ACT1(gA, i1a, f1a, g1a, o1a, s1a, cA)
    ACT1(gB, i1b, f1b, g1b, o1b, s1b, cB)
    ACT1(gC, i1c, f1c, g1c, o1c, s1c, cC)
    if (wv == 0) ACT1(g24, i1d, f1d, g1d, o1d, s1d, cD)
    __syncthreads();  // M

    f16x8 n0 = LDH(H1w, 0), n1 = LDH(H1w, 1), n2 = LDH(H1w, 2), n3 = LDH(H1w, 3);
    f32x4 dA = pA, dB = pB, dC = pC;
    CH4(dA, W2a0, W2a1, W2a2, W2a3, n0, n1, n2, n3)
    CH4(dB, W2b0, W2b1, W2b2, W2b3, n0, n1, n2, n3)
    CH4(dC, W2c0, W2c1, W2c2, W2c3, n0, n1, n2, n3)
    ACT2(dA, i2a, f2a, g2a, o2a, s2a, cA)
    ACT2(dB, i2b, f2b, g2b, o2b, s2b, cB)
    ACT2(dC, i2c, f2c, g2c, o2c, s2c, cC)
    if (wv == 0) {
      f32x4 d24 = p24;
      CH4(d24, V2[lane], V2[64+lane], V2[128+lane], V2[192+lane], n0, n1, n2, n3)
      ACT2(d24, i2d, f2d, g2d, o2d, s2d, cD)
    }
    __syncthreads();  // S
  }

  // final output y(TT-1)
  {
    float y0, y1; YCOMP(y0, y1)
    if (wv == 7) {
      if (lane == 0)  out[(size_t)b0 * TT + (TT - 1)] = y0;
      if (lane == 32) out[(size_t)(b0 + 1) * TT + (TT - 1)] = y1;
    }
  }
}

extern "C" void kernel_launch(void* const* d_in, const int* in_sizes, int n_in,
                              void* d_out, int out_size, void* d_ws, size_t ws_size,
                              hipStream_t stream) {
  const float* input = (const float*)d_in[0];
  const float* Wih1  = (const float*)d_in[1];
  const float* Whh1  = (const float*)d_in[2];
  const float* bih1  = (const float*)d_in[3];
  const float* bhh1  = (const float*)d_in[4];
  const float* Wih2  = (const float*)d_in[5];
  const float* Whh2  = (const float*)d_in[6];
  const float* bih2  = (const float*)d_in[7];
  const float* bhh2  = (const float*)d_in[8];
  const float* Wlin  = (const float*)d_in[9];
  const float* blin  = (const float*)d_in[10];
  const int*   futp  = (const int*)d_in[11];
  float* out = (float*)d_out;

  dim3 grid(B_TOTAL / NB);  // 256 blocks, 1 per CU
  dim3 block(BLOCK);
  hipLaunchKernelGGL(lstm2_mfma2, grid, block, 0, stream,
                     input, Wih1, Whh1, bih1, bhh1, Wih2, Whh2, bih2, bhh2,
                     Wlin, blin, futp, out);
}

// Round 10
// 3921.832 us; speedup vs baseline: 1.1282x; 1.1282x over previous
//
#include <hip/hip_runtime.h>
#include <stdint.h>

#define HID 100
#define B_TOTAL 512
#define T_IN 1000
#define NB 2
#define BLOCK 512   // 8 waves, 2/EU -> 256 unified cap; keep arch demand ~180 (R5 regime)

typedef __fp16 f16x8 __attribute__((ext_vector_type(8)));
typedef float f32x4 __attribute__((ext_vector_type(4)));

// Transposed MFMA: A = weight tile (m=permuted gate), B = h (n=batch col).
// C row r=4q+reg (q=lane>>4) -> cell (tileBase+q), gate reg; col = lane&15 = batch.
#define MF(A_, B_, C_) __builtin_amdgcn_mfma_f32_16x16x32_f16((A_), (B_), (C_), 0, 0, 0)

__device__ __forceinline__ float sigm(float x) { return 1.0f / (1.0f + __expf(-x)); }
__device__ __forceinline__ float tanh_fast(float x) {
  float e = __expf(2.0f * x);
  return 1.0f - 2.0f / (e + 1.0f);
}

// weight elem fetchers (0 outside real range). j = original gate row (0..399).
__device__ __forceinline__ __fp16 w1e(const float* Whh1, const float* Wih1, int j, int k) {
  float v = 0.f; if (k < 100) v = Whh1[j * 100 + k]; else if (k == 100) v = Wih1[j];
  return (__fp16)v;
}
__device__ __forceinline__ __fp16 w2e(const float* Wih2, int j, int k) {
  float v = 0.f; if (k < 100) v = Wih2[j * 100 + k]; return (__fp16)v;
}
__device__ __forceinline__ __fp16 w3e(const float* Whh2, int j, int k) {
  float v = 0.f; if (k < 100) v = Whh2[j * 100 + k]; return (__fp16)v;
}

__device__ __forceinline__ f16x8 mkw1(const float* Whh1, const float* Wih1, int j, int KT, int kg) {
  f16x8 r;
#pragma unroll
  for (int e = 0; e < 8; e++) r[e] = w1e(Whh1, Wih1, j, KT * 32 + kg * 8 + e);
  return r;
}
__device__ __forceinline__ f16x8 mkw2(const float* Wih2, int j, int KT, int kg) {
  f16x8 r;
#pragma unroll
  for (int e = 0; e < 8; e++) r[e] = w2e(Wih2, j, KT * 32 + kg * 8 + e);
  return r;
}
__device__ __forceinline__ f16x8 mkw3(const float* Whh2, int j, int KT, int kg) {
  f16x8 r;
#pragma unroll
  for (int e = 0; e < 8; e++) r[e] = w3e(Whh2, j, KT * 32 + kg * 8 + e);
  return r;
}
// combined tail frag: k0..3 = Wih2[j][96..99], k4..7 = Whh2[j][96..99], k>=8 -> 0
__device__ __forceinline__ f16x8 mktl(const float* Wih2, const float* Whh2, int j, int kg) {
  f16x8 r;
#pragma unroll
  for (int e = 0; e < 8; e++) {
    float v = 0.f;
    if (kg == 0) v = (e < 4) ? Wih2[j * 100 + 96 + e] : Whh2[j * 100 + 92 + e];
    r[e] = (__fp16)v;
  }
  return r;
}

__global__ __launch_bounds__(BLOCK, 2) void lstm2_t2(
    const float* __restrict__ input,
    const float* __restrict__ Wih1, const float* __restrict__ Whh1,
    const float* __restrict__ bih1, const float* __restrict__ bhh1,
    const float* __restrict__ Wih2, const float* __restrict__ Whh2,
    const float* __restrict__ bih2, const float* __restrict__ bhh2,
    const float* __restrict__ Wlin, const float* __restrict__ blin,
    const int* __restrict__ futp,
    float* __restrict__ out)
{
  // compact h buffers (per K-tile: [col0 32 | col1 32 | zero 16]), parity-double
  __shared__ __align__(16) __fp16 Hb1[2][320];   // h1 (+x at tile3 elem 4)
  __shared__ __align__(16) __fp16 Hb2[2][320];   // h2
  __shared__ __align__(16) __fp16 TB[2][24];     // tails: [col0 8 | col1 8 | zero 8]
  __shared__ __align__(16) __fp16 V1[4 * 512];   // tile-24 W1 frags (wave 0)
  __shared__ __align__(16) __fp16 V2[3 * 512];   // tile-24 W2 frags
  __shared__ __align__(16) __fp16 V3[3 * 512];   // tile-24 W3 frags
  __shared__ __align__(16) __fp16 VT[512];       // tile-24 tail frag
  __shared__ __align__(16) float bs1f[400];      // layer-1 bias (i,f,g,o) per cell
  __shared__ __align__(16) float bs2f[400];      // layer-2 bias
  __shared__ float xrow[NB][T_IN];
  __shared__ __align__(16) float ybuf[NB][104];
  __shared__ __align__(16) float wls[104];

  const int tid = threadIdx.x;
  const int lane = tid & 63;
  const int wv = tid >> 6;
  const int q = lane >> 4;    // K-group / cell-in-quad / C row-quad
  const int bb = lane & 15;   // batch col (real 0,1); gate selector on A side
  const int b0 = blockIdx.x * NB;
  const int F = futp[0];
  const int TT = T_IN + F;

  // ---------------- init ----------------
  for (int i = tid; i < NB * T_IN; i += BLOCK) {
    int b = i / T_IN, t = i % T_IN;
    xrow[b][t] = input[(size_t)(b0 + b) * T_IN + t];
  }
  if (tid < 320) { ((uint32_t*)Hb1)[tid] = 0u; ((uint32_t*)Hb2)[tid] = 0u; }
  if (tid < 24) ((uint32_t*)TB)[tid] = 0u;
  if (tid < 104) wls[tid] = (tid < HID) ? Wlin[tid] : 0.f;
  if (tid < 208) ((float*)ybuf)[tid] = 0.f;
  if (tid < 100) {
    int c = tid;
    *(f32x4*)&bs1f[4 * c] = (f32x4){bih1[c] + bhh1[c], bih1[100 + c] + bhh1[100 + c],
                                    bih1[200 + c] + bhh1[200 + c], bih1[300 + c] + bhh1[300 + c]};
  } else if (tid < 200) {
    int c = tid - 100;
    *(f32x4*)&bs2f[4 * c] = (f32x4){bih2[c] + bhh2[c], bih2[100 + c] + bhh2[100 + c],
                                    bih2[200 + c] + bhh2[200 + c], bih2[300 + c] + bhh2[300 + c]};
  }
  // tile-24 frags -> LDS (tids 0..63 emulate wave-0 lanes; R9-verified pattern)
  if (tid < 64) {
    int l = tid, bbl = l & 15, kgl = l >> 4;
    int j24 = (bbl & 3) * 100 + 96 + (bbl >> 2);
    f16x8* Vv1 = (f16x8*)V1; f16x8* Vv2 = (f16x8*)V2; f16x8* Vv3 = (f16x8*)V3; f16x8* Vvt = (f16x8*)VT;
    Vv1[0 * 64 + l] = mkw1(Whh1, Wih1, j24, 0, kgl);
    Vv1[1 * 64 + l] = mkw1(Whh1, Wih1, j24, 1, kgl);
    Vv1[2 * 64 + l] = mkw1(Whh1, Wih1, j24, 2, kgl);
    Vv1[3 * 64 + l] = mkw1(Whh1, Wih1, j24, 3, kgl);
    Vv2[0 * 64 + l] = mkw2(Wih2, j24, 0, kgl);
    Vv2[1 * 64 + l] = mkw2(Wih2, j24, 1, kgl);
    Vv2[2 * 64 + l] = mkw2(Wih2, j24, 2, kgl);
    Vv3[0 * 64 + l] = mkw3(Whh2, j24, 0, kgl);
    Vv3[1 * 64 + l] = mkw3(Whh2, j24, 1, kgl);
    Vv3[2 * 64 + l] = mkw3(Whh2, j24, 2, kgl);
    Vvt[l] = mktl(Wih2, Whh2, j24, kgl);
  }

  // ---------------- register weight frags (3 tiles/wave) ----------------
  const int T0 = wv, T1 = 8 + wv, T2 = 16 + wv;
  const int jA = (bb & 3) * 100 + 4 * T0 + (bb >> 2);
  const int jB = (bb & 3) * 100 + 4 * T1 + (bb >> 2);
  const int jC = (bb & 3) * 100 + 4 * T2 + (bb >> 2);
  f16x8 W1a0 = mkw1(Whh1, Wih1, jA, 0, q), W1a1 = mkw1(Whh1, Wih1, jA, 1, q),
        W1a2 = mkw1(Whh1, Wih1, jA, 2, q), W1a3 = mkw1(Whh1, Wih1, jA, 3, q);
  f16x8 W1b0 = mkw1(Whh1, Wih1, jB, 0, q), W1b1 = mkw1(Whh1, Wih1, jB, 1, q),
        W1b2 = mkw1(Whh1, Wih1, jB, 2, q), W1b3 = mkw1(Whh1, Wih1, jB, 3, q);
  f16x8 W1c0 = mkw1(Whh1, Wih1, jC, 0, q), W1c1 = mkw1(Whh1, Wih1, jC, 1, q),
        W1c2 = mkw1(Whh1, Wih1, jC, 2, q), W1c3 = mkw1(Whh1, Wih1, jC, 3, q);
  f16x8 W2a0 = mkw2(Wih2, jA, 0, q), W2a1 = mkw2(Wih2, jA, 1, q), W2a2 = mkw2(Wih2, jA, 2, q);
  f16x8 W2b0 = mkw2(Wih2, jB, 0, q), W2b1 = mkw2(Wih2, jB, 1, q), W2b2 = mkw2(Wih2, jB, 2, q);
  f16x8 W2c0 = mkw2(Wih2, jC, 0, q), W2c1 = mkw2(Wih2, jC, 1, q), W2c2 = mkw2(Wih2, jC, 2, q);
  f16x8 W3a0 = mkw3(Whh2, jA, 0, q), W3a1 = mkw3(Whh2, jA, 1, q), W3a2 = mkw3(Whh2, jA, 2, q);
  f16x8 W3b0 = mkw3(Whh2, jB, 0, q), W3b1 = mkw3(Whh2, jB, 1, q), W3b2 = mkw3(Whh2, jB, 2, q);
  f16x8 W3c0 = mkw3(Whh2, jC, 0, q), W3c1 = mkw3(Whh2, jC, 1, q), W3c2 = mkw3(Whh2, jC, 2, q);
  f16x8 WtA = mktl(Wih2, Whh2, jA, q), WtB = mktl(Wih2, Whh2, jB, q), WtC = mktl(Wih2, Whh2, jC, q);

  const int cA = 4 * T0 + q, cB = 4 * T1 + q, cC = 4 * T2 + q, cD = 96 + q;
  float s1a = 0, s1b = 0, s1c = 0, s1d = 0, s2a = 0, s2b = 0, s2c = 0, s2d = 0;

  const int roff = (bb < 2) ? bb * 32 + q * 8 : 64;   // compact-tile read offset
  const int rofft = (bb < 2) ? bb * 8 : 16;           // tail-chunk read offset
  const float blin0 = blin[0];

  __syncthreads();
  if (tid < 2) Hb1[0][3 * 80 + tid * 32 + 4] = (__fp16)xrow[tid][0];  // x(0)
  __syncthreads();

#define LDHF(P_, T_) (*(const f16x8*)&(P_)[(T_) * 80 + roff])

#define YCOMP(Y0_, Y1_) { \
    float acc = 0.0f; int sl = lane & 31; \
    if (sl < 26) { float4 hv = ((const float4*)ybuf[lane >> 5])[sl]; \
      float4 wl4 = ((const float4*)wls)[sl]; \
      acc = hv.x*wl4.x + hv.y*wl4.y + hv.z*wl4.z + hv.w*wl4.w; } \
    acc += __shfl_down(acc, 16, 32); acc += __shfl_down(acc, 8, 32); \
    acc += __shfl_down(acc, 4, 32);  acc += __shfl_down(acc, 2, 32); \
    acc += __shfl_down(acc, 1, 32); \
    Y0_ = __shfl(acc, 0, 64) + blin0; Y1_ = __shfl(acc, 32, 64) + blin0; }

#define ACT1(CF, ST, CI) { \
    float gi = CF[0], gf = CF[1], gg = CF[2], go = CF[3]; \
    ST = sigm(gf) * (ST) + sigm(gi) * tanh_fast(gg); \
    float hv = sigm(go) * tanh_fast(ST); \
    if (bb < 2) H1w[((CI) >> 5) * 80 + bb * 32 + ((CI) & 31)] = (__fp16)hv; }

#define ACT1T(CF, ST, CI) { \
    float gi = CF[0], gf = CF[1], gg = CF[2], go = CF[3]; \
    ST = sigm(gf) * (ST) + sigm(gi) * tanh_fast(gg); \
    float hv = sigm(go) * tanh_fast(ST); \
    if (bb < 2) { H1w[((CI) >> 5) * 80 + bb * 32 + ((CI) & 31)] = (__fp16)hv; \
                  TBw[bb * 8 + ((CI) - 96)] = (__fp16)hv; } }

#define ACT2(CF, ST, CI) { \
    float gi = CF[0], gf = CF[1], gg = CF[2], go = CF[3]; \
    ST = sigm(gf) * (ST) + sigm(gi) * tanh_fast(gg); \
    float hv = sigm(go) * tanh_fast(ST); \
    if (bb < 2) { H2w[((CI) >> 5) * 80 + bb * 32 + ((CI) & 31)] = (__fp16)hv; \
                  ybuf[bb][CI] = hv; } }

#define ACT2T(CF, ST, CI) { \
    float gi = CF[0], gf = CF[1], gg = CF[2], go = CF[3]; \
    ST = sigm(gf) * (ST) + sigm(gi) * tanh_fast(gg); \
    float hv = sigm(go) * tanh_fast(ST); \
    if (bb < 2) { H2w[((CI) >> 5) * 80 + bb * 32 + ((CI) & 31)] = (__fp16)hv; \
                  ybuf[bb][CI] = hv; \
                  TBa[bb * 8 + 4 + ((CI) - 96)] = (__fp16)hv; } }

  // gate chains: A-operand = weights, B-operand = h, C-init = bias vector
#define PHASE_A_BODY { \
    f32x4 b1A = *(const f32x4*)&bs1f[4 * cA], b1B = *(const f32x4*)&bs1f[4 * cB], \
          b1C = *(const f32x4*)&bs1f[4 * cC]; \
    f32x4 b2A = *(const f32x4*)&bs2f[4 * cA], b2B = *(const f32x4*)&bs2f[4 * cB], \
          b2C = *(const f32x4*)&bs2f[4 * cC]; \
    f32x4 gA = MF(W1a0, x0, b1A); gA = MF(W1a1, x1, gA); gA = MF(W1a2, x2, gA); gA = MF(W1a3, x3, gA); \
    f32x4 gB = MF(W1b0, x0, b1B); gB = MF(W1b1, x1, gB); gB = MF(W1b2, x2, gB); gB = MF(W1b3, x3, gB); \
    f32x4 gC = MF(W1c0, x0, b1C); gC = MF(W1c1, x1, gC); gC = MF(W1c2, x2, gC); gC = MF(W1c3, x3, gC); \
    pA = MF(W3a0, z0, b2A); pA = MF(W3a1, z1, pA); pA = MF(W3a2, z2, pA); \
    pB = MF(W3b0, z0, b2B); pB = MF(W3b1, z1, pB); pB = MF(W3b2, z2, pB); \
    pC = MF(W3c0, z0, b2C); pC = MF(W3c1, z1, pC); pC = MF(W3c2, z2, pC); \
    if (wv == 0) { \
      f32x4 b1D = *(const f32x4*)&bs1f[4 * cD], b2D = *(const f32x4*)&bs2f[4 * cD]; \
      const f16x8* Vv1 = (const f16x8*)V1; const f16x8* Vv3 = (const f16x8*)V3; \
      g24 = MF(Vv1[lane], x0, b1D); g24 = MF(Vv1[64 + lane], x1, g24); \
      g24 = MF(Vv1[128 + lane], x2, g24); g24 = MF(Vv1[192 + lane], x3, g24); \
      p24 = MF(Vv3[lane], z0, b2D); p24 = MF(Vv3[64 + lane], z1, p24); p24 = MF(Vv3[128 + lane], z2, p24); \
    } \
    ACT1(gA, s1a, cA) ACT1(gB, s1b, cB) ACT1(gC, s1c, cC) \
    if (wv == 0) ACT1T(g24, s1d, cD) }

#define PHASE_B_BODY { \
    f16x8 n0 = LDHF(H1w, 0), n1 = LDHF(H1w, 1), n2 = LDHF(H1w, 2); \
    f16x8 nt = *(const f16x8*)&TBw[rofft]; \
    f32x4 dA = MF(W2a0, n0, pA); dA = MF(W2a1, n1, dA); dA = MF(W2a2, n2, dA); dA = MF(WtA, nt, dA); \
    f32x4 dB = MF(W2b0, n0, pB); dB = MF(W2b1, n1, dB); dB = MF(W2b2, n2, dB); dB = MF(WtB, nt, dB); \
    f32x4 dC = MF(W2c0, n0, pC); dC = MF(W2c1, n1, dC); dC = MF(W2c2, n2, dC); dC = MF(WtC, nt, dC); \
    ACT2(dA, s2a, cA) ACT2(dB, s2b, cB) ACT2(dC, s2c, cC) \
    if (wv == 0) { \
      const f16x8* Vv2 = (const f16x8*)V2; const f16x8* Vvt = (const f16x8*)VT; \
      f32x4 d24 = MF(Vv2[lane], n0, p24); d24 = MF(Vv2[64 + lane], n1, d24); \
      d24 = MF(Vv2[128 + lane], n2, d24); d24 = MF(Vvt[lane], nt, d24); \
      ACT2T(d24, s2d, cD) \
    } }

  // ================= teacher-forced: 2 barriers/step =================
  for (int t = 0; t < T_IN; t++) {
    const __fp16* H1r = Hb1[t & 1];
    const __fp16* H2r = Hb2[t & 1];
    __fp16* H1w = Hb1[(t + 1) & 1];
    __fp16* H2w = Hb2[(t + 1) & 1];
    __fp16* TBw = TB[(t + 1) & 1];
    __fp16* TBa = TB[t & 1];

    f16x8 x0 = LDHF(H1r, 0), x1 = LDHF(H1r, 1), x2 = LDHF(H1r, 2), x3 = LDHF(H1r, 3);
    f16x8 z0 = LDHF(H2r, 0), z1 = LDHF(H2r, 1), z2 = LDHF(H2r, 2);
    f32x4 pA, pB, pC, g24, p24;
    if (wv == 7 && t > 0) {   // y(t-1) off critical path
      float y0, y1; YCOMP(y0, y1)
      if (lane == 0)  out[(size_t)b0 * TT + (t - 1)] = y0;
      if (lane == 32) out[(size_t)(b0 + 1) * TT + (t - 1)] = y1;
    }
    PHASE_A_BODY
    if (tid < 2 && t + 1 < T_IN)
      H1w[3 * 80 + tid * 32 + 4] = (__fp16)xrow[tid][t + 1];   // x(t+1)
    __syncthreads();  // M: h1(t) + tails visible
    PHASE_B_BODY
    __syncthreads();  // S: h2(t), ybuf(t) visible
  }

  // ================= autoregressive: 2 barriers/step =================
  for (int t = T_IN; t < TT; t++) {
    const __fp16* H1r = Hb1[t & 1];
    const __fp16* H2r = Hb2[t & 1];
    __fp16* H1w = Hb1[(t + 1) & 1];
    __fp16* H2w = Hb2[(t + 1) & 1];
    __fp16* TBw = TB[(t + 1) & 1];
    __fp16* TBa = TB[t & 1];

    float y0, y1; YCOMP(y0, y1)         // redundant in all waves: feedback w/o barrier
    if (wv == 7) {
      if (lane == 0)  out[(size_t)b0 * TT + (t - 1)] = y0;
      if (lane == 32) out[(size_t)(b0 + 1) * TT + (t - 1)] = y1;
    }
    f16x8 x0 = LDHF(H1r, 0), x1 = LDHF(H1r, 1), x2 = LDHF(H1r, 2), x3 = LDHF(H1r, 3);
    if (lane < 2) x3[4] = (__fp16)((lane == 0) ? y0 : y1);  // x(t)=y(t-1) at k=100
    f16x8 z0 = LDHF(H2r, 0), z1 = LDHF(H2r, 1), z2 = LDHF(H2r, 2);
    f32x4 pA, pB, pC, g24, p24;
    PHASE_A_BODY
    __syncthreads();  // M
    PHASE_B_BODY
    __syncthreads();  // S
  }

  {  // final y(TT-1)
    float y0, y1; YCOMP(y0, y1)
    if (wv == 7) {
      if (lane == 0)  out[(size_t)b0 * TT + (TT - 1)] = y0;
      if (lane == 32) out[(size_t)(b0 + 1) * TT + (TT - 1)] = y1;
    }
  }
}

extern "C" void kernel_launch(void* const* d_in, const int* in_sizes, int n_in,
                              void* d_out, int out_size, void* d_ws, size_t ws_size,
                              hipStream_t stream) {
  const float* input = (const float*)d_in[0];
  const float* Wih1  = (const float*)d_in[1];
  const float* Whh1  = (const float*)d_in[2];
  const float* bih1  = (const float*)d_in[3];
  const float* bhh1  = (const float*)d_in[4];
  const float* Wih2  = (const float*)d_in[5];
  const float* Whh2  = (const float*)d_in[6];
  const float* bih2  = (const float*)d_in[7];
  const float* bhh2  = (const float*)d_in[8];
  const float* Wlin  = (const float*)d_in[9];
  const float* blin  = (const float*)d_in[10];
  const int*   futp  = (const int*)d_in[11];
  float* out = (float*)d_out;

  dim3 grid(B_TOTAL / NB);  // 256 blocks, 1 per CU
  dim3 block(BLOCK);
  hipLaunchKernelGGL(lstm2_t2, grid, block, 0, stream,
                     input, Wih1, Whh1, bih1, bhh1, Wih2, Whh2, bih2, bhh2,
                     Wlin, blin, futp, out);
}

// Round 11
// 2444.559 us; speedup vs baseline: 1.8100x; 1.6043x over previous
//
#include <hip/hip_runtime.h>
#include <stdint.h>

#define HID 100
#define B_TOTAL 512
#define T_IN 1000
#define NB 2
#define BLOCK 512   // 8 waves, 2/EU -> 256 unified cap; arch demand ~180 (R5 regime)

typedef __fp16 f16x8 __attribute__((ext_vector_type(8)));
typedef float f32x4 __attribute__((ext_vector_type(4)));

// Transposed MFMA: A = weight tile (m=permuted gate), B = h (n=batch col).
// C row r=4q+reg (q=lane>>4) -> cell (tileBase+q), gate reg; col = lane&15 = batch.
#define MF(A_, B_, C_) __builtin_amdgcn_mfma_f32_16x16x32_f16((A_), (B_), (C_), 0, 0, 0)

// ---- fast activation math: raw v_exp_f32 / v_rcp_f32 (~1 ulp each).
// R10 post-mortem: non-fast-math sigm/tanh compile to full div sequences
// (~87 VALU/act) -> VALUBusy 69%. These cut it ~4x.
#if __has_builtin(__builtin_amdgcn_exp2f)
#define EXP2F(x) __builtin_amdgcn_exp2f(x)
#else
#define EXP2F(x) exp2f(x)
#endif
#if __has_builtin(__builtin_amdgcn_rcpf)
#define RCPF(x) __builtin_amdgcn_rcpf(x)
#else
#define RCPF(x) (1.0f / (x))
#endif
#define LOG2E 1.44269504f
__device__ __forceinline__ float sigm(float x) {
  return RCPF(1.0f + EXP2F(-LOG2E * x));
}
__device__ __forceinline__ float tanh_fast(float x) {
  return 1.0f - 2.0f * RCPF(EXP2F((2.0f * LOG2E) * x) + 1.0f);
}

// weight elem fetchers (0 outside real range). j = original gate row (0..399).
__device__ __forceinline__ __fp16 w1e(const float* Whh1, const float* Wih1, int j, int k) {
  float v = 0.f; if (k < 100) v = Whh1[j * 100 + k]; else if (k == 100) v = Wih1[j];
  return (__fp16)v;
}
__device__ __forceinline__ __fp16 w2e(const float* Wih2, int j, int k) {
  float v = 0.f; if (k < 100) v = Wih2[j * 100 + k]; return (__fp16)v;
}
__device__ __forceinline__ __fp16 w3e(const float* Whh2, int j, int k) {
  float v = 0.f; if (k < 100) v = Whh2[j * 100 + k]; return (__fp16)v;
}

__device__ __forceinline__ f16x8 mkw1(const float* Whh1, const float* Wih1, int j, int KT, int kg) {
  f16x8 r;
#pragma unroll
  for (int e = 0; e < 8; e++) r[e] = w1e(Whh1, Wih1, j, KT * 32 + kg * 8 + e);
  return r;
}
__device__ __forceinline__ f16x8 mkw2(const float* Wih2, int j, int KT, int kg) {
  f16x8 r;
#pragma unroll
  for (int e = 0; e < 8; e++) r[e] = w2e(Wih2, j, KT * 32 + kg * 8 + e);
  return r;
}
__device__ __forceinline__ f16x8 mkw3(const float* Whh2, int j, int KT, int kg) {
  f16x8 r;
#pragma unroll
  for (int e = 0; e < 8; e++) r[e] = w3e(Whh2, j, KT * 32 + kg * 8 + e);
  return r;
}
// combined tail frag: k0..3 = Wih2[j][96..99], k4..7 = Whh2[j][96..99], k>=8 -> 0
__device__ __forceinline__ f16x8 mktl(const float* Wih2, const float* Whh2, int j, int kg) {
  f16x8 r;
#pragma unroll
  for (int e = 0; e < 8; e++) {
    float v = 0.f;
    if (kg == 0) v = (e < 4) ? Wih2[j * 100 + 96 + e] : Whh2[j * 100 + 92 + e];
    r[e] = (__fp16)v;
  }
  return r;
}

__global__ __launch_bounds__(BLOCK, 2) void lstm2_t2(
    const float* __restrict__ input,
    const float* __restrict__ Wih1, const float* __restrict__ Whh1,
    const float* __restrict__ bih1, const float* __restrict__ bhh1,
    const float* __restrict__ Wih2, const float* __restrict__ Whh2,
    const float* __restrict__ bih2, const float* __restrict__ bhh2,
    const float* __restrict__ Wlin, const float* __restrict__ blin,
    const int* __restrict__ futp,
    float* __restrict__ out)
{
  // compact h buffers (per K-tile: [col0 32 | col1 32 | zero 16]), parity-double
  __shared__ __align__(16) __fp16 Hb1[2][320];   // h1 (+x at tile3 elem 4)
  __shared__ __align__(16) __fp16 Hb2[2][320];   // h2
  __shared__ __align__(16) __fp16 TB[2][24];     // tails: [col0 8 | col1 8 | zero 8]
  __shared__ __align__(16) __fp16 V1[4 * 512];   // tile-24 W1 frags (wave 0)
  __shared__ __align__(16) __fp16 V2[3 * 512];   // tile-24 W2 frags
  __shared__ __align__(16) __fp16 V3[3 * 512];   // tile-24 W3 frags
  __shared__ __align__(16) __fp16 VT[512];       // tile-24 tail frag
  __shared__ __align__(16) float bs1f[400];      // layer-1 bias (i,f,g,o) per cell
  __shared__ __align__(16) float bs2f[400];      // layer-2 bias
  __shared__ float xrow[NB][T_IN];
  __shared__ __align__(16) float ybuf[NB][104];
  __shared__ __align__(16) float wls[104];

  const int tid = threadIdx.x;
  const int lane = tid & 63;
  const int wv = tid >> 6;
  const int q = lane >> 4;    // K-group / cell-in-quad / C row-quad
  const int bb = lane & 15;   // batch col (real 0,1); gate selector on A side
  const int b0 = blockIdx.x * NB;
  const int F = futp[0];
  const int TT = T_IN + F;

  // ---------------- init ----------------
  for (int i = tid; i < NB * T_IN; i += BLOCK) {
    int b = i / T_IN, t = i % T_IN;
    xrow[b][t] = input[(size_t)(b0 + b) * T_IN + t];
  }
  if (tid < 320) { ((uint32_t*)Hb1)[tid] = 0u; ((uint32_t*)Hb2)[tid] = 0u; }
  if (tid < 24) ((uint32_t*)TB)[tid] = 0u;
  if (tid < 104) wls[tid] = (tid < HID) ? Wlin[tid] : 0.f;
  if (tid < 208) ((float*)ybuf)[tid] = 0.f;
  if (tid < 100) {
    int c = tid;
    *(f32x4*)&bs1f[4 * c] = (f32x4){bih1[c] + bhh1[c], bih1[100 + c] + bhh1[100 + c],
                                    bih1[200 + c] + bhh1[200 + c], bih1[300 + c] + bhh1[300 + c]};
  } else if (tid < 200) {
    int c = tid - 100;
    *(f32x4*)&bs2f[4 * c] = (f32x4){bih2[c] + bhh2[c], bih2[100 + c] + bhh2[100 + c],
                                    bih2[200 + c] + bhh2[200 + c], bih2[300 + c] + bhh2[300 + c]};
  }
  // tile-24 frags -> LDS (tids 0..63 emulate wave-0 lanes; R9/R10-verified)
  if (tid < 64) {
    int l = tid, bbl = l & 15, kgl = l >> 4;
    int j24 = (bbl & 3) * 100 + 96 + (bbl >> 2);
    f16x8* Vv1 = (f16x8*)V1; f16x8* Vv2 = (f16x8*)V2; f16x8* Vv3 = (f16x8*)V3; f16x8* Vvt = (f16x8*)VT;
    Vv1[0 * 64 + l] = mkw1(Whh1, Wih1, j24, 0, kgl);
    Vv1[1 * 64 + l] = mkw1(Whh1, Wih1, j24, 1, kgl);
    Vv1[2 * 64 + l] = mkw1(Whh1, Wih1, j24, 2, kgl);
    Vv1[3 * 64 + l] = mkw1(Whh1, Wih1, j24, 3, kgl);
    Vv2[0 * 64 + l] = mkw2(Wih2, j24, 0, kgl);
    Vv2[1 * 64 + l] = mkw2(Wih2, j24, 1, kgl);
    Vv2[2 * 64 + l] = mkw2(Wih2, j24, 2, kgl);
    Vv3[0 * 64 + l] = mkw3(Whh2, j24, 0, kgl);
    Vv3[1 * 64 + l] = mkw3(Whh2, j24, 1, kgl);
    Vv3[2 * 64 + l] = mkw3(Whh2, j24, 2, kgl);
    Vvt[l] = mktl(Wih2, Whh2, j24, kgl);
  }

  // ---------------- register weight frags (3 tiles/wave) ----------------
  const int T0 = wv, T1 = 8 + wv, T2 = 16 + wv;
  const int jA = (bb & 3) * 100 + 4 * T0 + (bb >> 2);
  const int jB = (bb & 3) * 100 + 4 * T1 + (bb >> 2);
  const int jC = (bb & 3) * 100 + 4 * T2 + (bb >> 2);
  f16x8 W1a0 = mkw1(Whh1, Wih1, jA, 0, q), W1a1 = mkw1(Whh1, Wih1, jA, 1, q),
        W1a2 = mkw1(Whh1, Wih1, jA, 2, q), W1a3 = mkw1(Whh1, Wih1, jA, 3, q);
  f16x8 W1b0 = mkw1(Whh1, Wih1, jB, 0, q), W1b1 = mkw1(Whh1, Wih1, jB, 1, q),
        W1b2 = mkw1(Whh1, Wih1, jB, 2, q), W1b3 = mkw1(Whh1, Wih1, jB, 3, q);
  f16x8 W1c0 = mkw1(Whh1, Wih1, jC, 0, q), W1c1 = mkw1(Whh1, Wih1, jC, 1, q),
        W1c2 = mkw1(Whh1, Wih1, jC, 2, q), W1c3 = mkw1(Whh1, Wih1, jC, 3, q);
  f16x8 W2a0 = mkw2(Wih2, jA, 0, q), W2a1 = mkw2(Wih2, jA, 1, q), W2a2 = mkw2(Wih2, jA, 2, q);
  f16x8 W2b0 = mkw2(Wih2, jB, 0, q), W2b1 = mkw2(Wih2, jB, 1, q), W2b2 = mkw2(Wih2, jB, 2, q);
  f16x8 W2c0 = mkw2(Wih2, jC, 0, q), W2c1 = mkw2(Wih2, jC, 1, q), W2c2 = mkw2(Wih2, jC, 2, q);
  f16x8 W3a0 = mkw3(Whh2, jA, 0, q), W3a1 = mkw3(Whh2, jA, 1, q), W3a2 = mkw3(Whh2, jA, 2, q);
  f16x8 W3b0 = mkw3(Whh2, jB, 0, q), W3b1 = mkw3(Whh2, jB, 1, q), W3b2 = mkw3(Whh2, jB, 2, q);
  f16x8 W3c0 = mkw3(Whh2, jC, 0, q), W3c1 = mkw3(Whh2, jC, 1, q), W3c2 = mkw3(Whh2, jC, 2, q);
  f16x8 WtA = mktl(Wih2, Whh2, jA, q), WtB = mktl(Wih2, Whh2, jB, q), WtC = mktl(Wih2, Whh2, jC, q);

  const int cA = 4 * T0 + q, cB = 4 * T1 + q, cC = 4 * T2 + q, cD = 96 + q;
  float s1a = 0, s1b = 0, s1c = 0, s1d = 0, s2a = 0, s2b = 0, s2c = 0, s2d = 0;

  const int roff = (bb < 2) ? bb * 32 + q * 8 : 64;   // compact-tile read offset
  const int rofft = (bb < 2) ? bb * 8 : 16;           // tail-chunk read offset
  const float blin0 = blin[0];

  __syncthreads();
  if (tid < 2) Hb1[0][3 * 80 + tid * 32 + 4] = (__fp16)xrow[tid][0];  // x(0)
  __syncthreads();

#define LDHF(P_, T_) (*(const f16x8*)&(P_)[(T_) * 80 + roff])

#define YCOMP(Y0_, Y1_) { \
    float acc = 0.0f; int sl = lane & 31; \
    if (sl < 26) { float4 hv = ((const float4*)ybuf[lane >> 5])[sl]; \
      float4 wl4 = ((const float4*)wls)[sl]; \
      acc = hv.x*wl4.x + hv.y*wl4.y + hv.z*wl4.z + hv.w*wl4.w; } \
    acc += __shfl_down(acc, 16, 32); acc += __shfl_down(acc, 8, 32); \
    acc += __shfl_down(acc, 4, 32);  acc += __shfl_down(acc, 2, 32); \
    acc += __shfl_down(acc, 1, 32); \
    Y0_ = __shfl(acc, 0, 64) + blin0; Y1_ = __shfl(acc, 32, 64) + blin0; }

#define ACT1(CF, ST, CI) { \
    float gi = CF[0], gf = CF[1], gg = CF[2], go = CF[3]; \
    ST = sigm(gf) * (ST) + sigm(gi) * tanh_fast(gg); \
    float hv = sigm(go) * tanh_fast(ST); \
    if (bb < 2) H1w[((CI) >> 5) * 80 + bb * 32 + ((CI) & 31)] = (__fp16)hv; }

#define ACT1T(CF, ST, CI) { \
    float gi = CF[0], gf = CF[1], gg = CF[2], go = CF[3]; \
    ST = sigm(gf) * (ST) + sigm(gi) * tanh_fast(gg); \
    float hv = sigm(go) * tanh_fast(ST); \
    if (bb < 2) { H1w[((CI) >> 5) * 80 + bb * 32 + ((CI) & 31)] = (__fp16)hv; \
                  TBw[bb * 8 + ((CI) - 96)] = (__fp16)hv; } }

#define ACT2(CF, ST, CI) { \
    float gi = CF[0], gf = CF[1], gg = CF[2], go = CF[3]; \
    ST = sigm(gf) * (ST) + sigm(gi) * tanh_fast(gg); \
    float hv = sigm(go) * tanh_fast(ST); \
    if (bb < 2) { H2w[((CI) >> 5) * 80 + bb * 32 + ((CI) & 31)] = (__fp16)hv; \
                  ybuf[bb][CI] = hv; } }

#define ACT2T(CF, ST, CI) { \
    float gi = CF[0], gf = CF[1], gg = CF[2], go = CF[3]; \
    ST = sigm(gf) * (ST) + sigm(gi) * tanh_fast(gg); \
    float hv = sigm(go) * tanh_fast(ST); \
    if (bb < 2) { H2w[((CI) >> 5) * 80 + bb * 32 + ((CI) & 31)] = (__fp16)hv; \
                  ybuf[bb][CI] = hv; \
                  TBa[bb * 8 + 4 + ((CI) - 96)] = (__fp16)hv; } }

  // gate chains: A-operand = weights, B-operand = h, C-init = bias vector
#define PHASE_A_BODY { \
    f32x4 b1A = *(const f32x4*)&bs1f[4 * cA], b1B = *(const f32x4*)&bs1f[4 * cB], \
          b1C = *(const f32x4*)&bs1f[4 * cC]; \
    f32x4 b2A = *(const f32x4*)&bs2f[4 * cA], b2B = *(const f32x4*)&bs2f[4 * cB], \
          b2C = *(const f32x4*)&bs2f[4 * cC]; \
    f32x4 gA = MF(W1a0, x0, b1A); gA = MF(W1a1, x1, gA); gA = MF(W1a2, x2, gA); gA = MF(W1a3, x3, gA); \
    f32x4 gB = MF(W1b0, x0, b1B); gB = MF(W1b1, x1, gB); gB = MF(W1b2, x2, gB); gB = MF(W1b3, x3, gB); \
    f32x4 gC = MF(W1c0, x0, b1C); gC = MF(W1c1, x1, gC); gC = MF(W1c2, x2, gC); gC = MF(W1c3, x3, gC); \
    pA = MF(W3a0, z0, b2A); pA = MF(W3a1, z1, pA); pA = MF(W3a2, z2, pA); \
    pB = MF(W3b0, z0, b2B); pB = MF(W3b1, z1, pB); pB = MF(W3b2, z2, pB); \
    pC = MF(W3c0, z0, b2C); pC = MF(W3c1, z1, pC); pC = MF(W3c2, z2, pC); \
    if (wv == 0) { \
      f32x4 b1D = *(const f32x4*)&bs1f[4 * cD], b2D = *(const f32x4*)&bs2f[4 * cD]; \
      const f16x8* Vv1 = (const f16x8*)V1; const f16x8* Vv3 = (const f16x8*)V3; \
      g24 = MF(Vv1[lane], x0, b1D); g24 = MF(Vv1[64 + lane], x1, g24); \
      g24 = MF(Vv1[128 + lane], x2, g24); g24 = MF(Vv1[192 + lane], x3, g24); \
      p24 = MF(Vv3[lane], z0, b2D); p24 = MF(Vv3[64 + lane], z1, p24); p24 = MF(Vv3[128 + lane], z2, p24); \
    } \
    ACT1(gA, s1a, cA) ACT1(gB, s1b, cB) ACT1(gC, s1c, cC) \
    if (wv == 0) ACT1T(g24, s1d, cD) }

#define PHASE_B_BODY { \
    f16x8 n0 = LDHF(H1w, 0), n1 = LDHF(H1w, 1), n2 = LDHF(H1w, 2); \
    f16x8 nt = *(const f16x8*)&TBw[rofft]; \
    f32x4 dA = MF(W2a0, n0, pA); dA = MF(W2a1, n1, dA); dA = MF(W2a2, n2, dA); dA = MF(WtA, nt, dA); \
    f32x4 dB = MF(W2b0, n0, pB); dB = MF(W2b1, n1, dB); dB = MF(W2b2, n2, dB); dB = MF(WtB, nt, dB); \
    f32x4 dC = MF(W2c0, n0, pC); dC = MF(W2c1, n1, dC); dC = MF(W2c2, n2, dC); dC = MF(WtC, nt, dC); \
    ACT2(dA, s2a, cA) ACT2(dB, s2b, cB) ACT2(dC, s2c, cC) \
    if (wv == 0) { \
      const f16x8* Vv2 = (const f16x8*)V2; const f16x8* Vvt = (const f16x8*)VT; \
      f32x4 d24 = MF(Vv2[lane], n0, p24); d24 = MF(Vv2[64 + lane], n1, d24); \
      d24 = MF(Vv2[128 + lane], n2, d24); d24 = MF(Vvt[lane], nt, d24); \
      ACT2T(d24, s2d, cD) \
    } }

  // ================= teacher-forced: 2 barriers/step =================
  for (int t = 0; t < T_IN; t++) {
    const __fp16* H1r = Hb1[t & 1];
    const __fp16* H2r = Hb2[t & 1];
    __fp16* H1w = Hb1[(t + 1) & 1];
    __fp16* H2w = Hb2[(t + 1) & 1];
    __fp16* TBw = TB[(t + 1) & 1];
    __fp16* TBa = TB[t & 1];

    f16x8 x0 = LDHF(H1r, 0), x1 = LDHF(H1r, 1), x2 = LDHF(H1r, 2), x3 = LDHF(H1r, 3);
    f16x8 z0 = LDHF(H2r, 0), z1 = LDHF(H2r, 1), z2 = LDHF(H2r, 2);
    f32x4 pA, pB, pC, g24, p24;
    if (wv == 7 && t > 0) {   // y(t-1) off critical path
      float y0, y1; YCOMP(y0, y1)
      if (lane == 0)  out[(size_t)b0 * TT + (t - 1)] = y0;
      if (lane == 32) out[(size_t)(b0 + 1) * TT + (t - 1)] = y1;
    }
    PHASE_A_BODY
    if (tid < 2 && t + 1 < T_IN)
      H1w[3 * 80 + tid * 32 + 4] = (__fp16)xrow[tid][t + 1];   // x(t+1)
    __syncthreads();  // M: h1(t) + tails visible
    PHASE_B_BODY
    __syncthreads();  // S: h2(t), ybuf(t) visible
  }

  // ================= autoregressive: 2 barriers/step =================
  for (int t = T_IN; t < TT; t++) {
    const __fp16* H1r = Hb1[t & 1];
    const __fp16* H2r = Hb2[t & 1];
    __fp16* H1w = Hb1[(t + 1) & 1];
    __fp16* H2w = Hb2[(t + 1) & 1];
    __fp16* TBw = TB[(t + 1) & 1];
    __fp16* TBa = TB[t & 1];

    float y0, y1; YCOMP(y0, y1)         // redundant in all waves: feedback w/o barrier
    if (wv == 7) {
      if (lane == 0)  out[(size_t)b0 * TT + (t - 1)] = y0;
      if (lane == 32) out[(size_t)(b0 + 1) * TT + (t - 1)] = y1;
    }
    f16x8 x0 = LDHF(H1r, 0), x1 = LDHF(H1r, 1), x2 = LDHF(H1r, 2), x3 = LDHF(H1r, 3);
    if (lane < 2) x3[4] = (__fp16)((lane == 0) ? y0 : y1);  // x(t)=y(t-1) at k=100
    f16x8 z0 = LDHF(H2r, 0), z1 = LDHF(H2r, 1), z2 = LDHF(H2r, 2);
    f32x4 pA, pB, pC, g24, p24;
    PHASE_A_BODY
    __syncthreads();  // M
    PHASE_B_BODY
    __syncthreads();  // S
  }

  {  // final y(TT-1)
    float y0, y1; YCOMP(y0, y1)
    if (wv == 7) {
      if (lane == 0)  out[(size_t)b0 * TT + (TT - 1)] = y0;
      if (lane == 32) out[(size_t)(b0 + 1) * TT + (TT - 1)] = y1;
    }
  }
}

extern "C" void kernel_launch(void* const* d_in, const int* in_sizes, int n_in,
                              void* d_out, int out_size, void* d_ws, size_t ws_size,
                              hipStream_t stream) {
  const float* input = (const float*)d_in[0];
  const float* Wih1  = (const float*)d_in[1];
  const float* Whh1  = (const float*)d_in[2];
  const float* bih1  = (const float*)d_in[3];
  const float* bhh1  = (const float*)d_in[4];
  const float* Wih2  = (const float*)d_in[5];
  const float* Whh2  = (const float*)d_in[6];
  const float* bih2  = (const float*)d_in[7];
  const float* bhh2  = (const float*)d_in[8];
  const float* Wlin  = (const float*)d_in[9];
  const float* blin  = (const float*)d_in[10];
  const int*   futp  = (const int*)d_in[11];
  float* out = (float*)d_out;

  dim3 grid(B_TOTAL / NB);  // 256 blocks, 1 per CU
  dim3 block(BLOCK);
  hipLaunchKernelGGL(lstm2_t2, grid, block, 0, stream,
                     input, Wih1, Whh1, bih1, bhh1, Wih2, Whh2, bih2, bhh2,
                     Wlin, blin, futp, out);
}

// Round 12
// 1814.590 us; speedup vs baseline: 2.4383x; 1.3472x over previous
//
#include <hip/hip_runtime.h>
#include <stdint.h>

// Problem constants
#define HID 100
#define B_TOTAL 512
#define T_IN 1000
#define NB 2
#define BLOCK 512   // 8 waves, 2 waves/EU

typedef __fp16 f16x8 __attribute__((ext_vector_type(8)));
typedef float f32x4 __attribute__((ext_vector_type(4)));

#define MF(A, B, C) __builtin_amdgcn_mfma_f32_16x16x32_f16((A), (B), (C), 0, 0, 0)

// ---- fast activation math (R11-verified: absmax unchanged at 4.88e-4) ----
#if __has_builtin(__builtin_amdgcn_exp2f)
#define EXP2F(x) __builtin_amdgcn_exp2f(x)
#else
#define EXP2F(x) exp2f(x)
#endif
#if __has_builtin(__builtin_amdgcn_rcpf)
#define RCPF(x) __builtin_amdgcn_rcpf(x)
#else
#define RCPF(x) (1.0f / (x))
#endif
#define LOG2E 1.44269504f
__device__ __forceinline__ float sigm(float x) { return RCPF(1.0f + EXP2F(-LOG2E * x)); }
__device__ __forceinline__ float tanh_fast(float x) {
  return 1.0f - 2.0f * RCPF(EXP2F((2.0f * LOG2E) * x) + 1.0f);
}

// ---- compact A layout (R8-verified): per 32-K tile, 80 f16:
//   [0..31]=row m=0, [32..63]=row m=1, [64..71]=shared zero chunk, [72..79] pad
__device__ __forceinline__ int cidx(int k, int m) {   // write-side index
  return (k >> 5) * 80 + m * 32 + (k & 31);
}

// weight element fetchers (R8-verified; 0 in pad regions)
__device__ __forceinline__ __fp16 w1e(const float* Whh1, const float* Wih1, int j, int k) {
  float v = 0.0f;
  if (k < 100) v = Whh1[j * 100 + k];
  else if (k == 100) v = Wih1[j];
  return (__fp16)v;
}
__device__ __forceinline__ __fp16 w2e(const float* Wih2, const float* Whh2, int j, int k) {
  float v = 0.0f;
  if (k < 100) v = Wih2[j * 100 + k];
  else if (k >= 112 && k < 212) v = Whh2[j * 100 + (k - 112)];
  return (__fp16)v;
}

#define MKB1(J, KT) (f16x8){ \
  w1e(Whh1, Wih1, (J), (KT)*32 + kg*8 + 0), w1e(Whh1, Wih1, (J), (KT)*32 + kg*8 + 1), \
  w1e(Whh1, Wih1, (J), (KT)*32 + kg*8 + 2), w1e(Whh1, Wih1, (J), (KT)*32 + kg*8 + 3), \
  w1e(Whh1, Wih1, (J), (KT)*32 + kg*8 + 4), w1e(Whh1, Wih1, (J), (KT)*32 + kg*8 + 5), \
  w1e(Whh1, Wih1, (J), (KT)*32 + kg*8 + 6), w1e(Whh1, Wih1, (J), (KT)*32 + kg*8 + 7) }
#define MKB2(J, KT) (f16x8){ \
  w2e(Wih2, Whh2, (J), (KT)*32 + kg*8 + 0), w2e(Wih2, Whh2, (J), (KT)*32 + kg*8 + 1), \
  w2e(Wih2, Whh2, (J), (KT)*32 + kg*8 + 2), w2e(Wih2, Whh2, (J), (KT)*32 + kg*8 + 3), \
  w2e(Wih2, Whh2, (J), (KT)*32 + kg*8 + 4), w2e(Wih2, Whh2, (J), (KT)*32 + kg*8 + 5), \
  w2e(Wih2, Whh2, (J), (KT)*32 + kg*8 + 6), w2e(Wih2, Whh2, (J), (KT)*32 + kg*8 + 7) }

__global__ __launch_bounds__(BLOCK, 2) void lstm2_mfma(
    const float* __restrict__ input,  // [512,1000]
    const float* __restrict__ Wih1,   // [400,1]
    const float* __restrict__ Whh1,   // [400,100]
    const float* __restrict__ bih1,
    const float* __restrict__ bhh1,
    const float* __restrict__ Wih2,   // [400,100]
    const float* __restrict__ Whh2,   // [400,100]
    const float* __restrict__ bih2,
    const float* __restrict__ bhh2,
    const float* __restrict__ Wlin,   // [1,100]
    const float* __restrict__ blin,   // [1]
    const int* __restrict__ futp,
    float* __restrict__ out)          // [512, 1000+future]
{
  __shared__ __align__(16) __fp16 A1c[4 * 80];    // L1 A: k0..99=h1(t-1), k100=x(t)
  __shared__ __align__(16) __fp16 A2c[7 * 80];    // L2 A: k0..99=h1, k112..211=h2
  __shared__ __align__(16) __fp16 BL1h[4 * 512];  // B frags, N-tile 24 (wave 0)
  __shared__ __align__(16) __fp16 BL2h[7 * 512];
  __shared__ float2 gb2[400];        // gate pre-acts [n](batch0, batch1)
  __shared__ float xrow[NB][T_IN];   // staged inputs (8 KB)
  __shared__ float ybuf[NB][104];    // h2(t) f32 for y-dot (pads 0)
  __shared__ float wls[104];         // Wlin staged (pads 0)

  const int tid = threadIdx.x;
  const int lane = tid & 63;
  const int wv = tid >> 6;
  const int b0 = blockIdx.x * NB;
  const int F = futp[0];
  const int TT = T_IN + F;

  // ---------------- init: stage + zero ----------------
  for (int i = tid; i < NB * T_IN; i += BLOCK) {
    int b = i / T_IN, t = i % T_IN;
    xrow[b][t] = input[(size_t)(b0 + b) * T_IN + t];
  }
  if (tid < 160) ((uint32_t*)A1c)[tid] = 0u;
  if (tid < 280) ((uint32_t*)A2c)[tid] = 0u;
  if (tid < 104) wls[tid] = (tid < HID) ? Wlin[tid] : 0.0f;
  if (tid < 208) ((float*)ybuf)[tid] = 0.0f;

  // ---------------- register-resident B fragments (R8-verified) ----------------
  const int n15 = lane & 15;
  const int kg = (lane >> 4) & 3;
  const int j0 = (wv) * 16 + n15;        // N-tile wv
  const int j1 = (8 + wv) * 16 + n15;    // N-tile 8+wv
  const int j2 = (16 + wv) * 16 + n15;   // N-tile 16+wv
  f16x8 B1_0_0 = MKB1(j0, 0), B1_0_1 = MKB1(j0, 1), B1_0_2 = MKB1(j0, 2), B1_0_3 = MKB1(j0, 3);
  f16x8 B1_1_0 = MKB1(j1, 0), B1_1_1 = MKB1(j1, 1), B1_1_2 = MKB1(j1, 2), B1_1_3 = MKB1(j1, 3);
  f16x8 B1_2_0 = MKB1(j2, 0), B1_2_1 = MKB1(j2, 1), B1_2_2 = MKB1(j2, 2), B1_2_3 = MKB1(j2, 3);
  f16x8 B2_0_0 = MKB2(j0, 0), B2_0_1 = MKB2(j0, 1), B2_0_2 = MKB2(j0, 2), B2_0_3 = MKB2(j0, 3),
        B2_0_4 = MKB2(j0, 4), B2_0_5 = MKB2(j0, 5), B2_0_6 = MKB2(j0, 6);
  f16x8 B2_1_0 = MKB2(j1, 0), B2_1_1 = MKB2(j1, 1), B2_1_2 = MKB2(j1, 2), B2_1_3 = MKB2(j1, 3),
        B2_1_4 = MKB2(j1, 4), B2_1_5 = MKB2(j1, 5), B2_1_6 = MKB2(j1, 6);
  f16x8 B2_2_0 = MKB2(j2, 0), B2_2_1 = MKB2(j2, 1), B2_2_2 = MKB2(j2, 2), B2_2_3 = MKB2(j2, 3),
        B2_2_4 = MKB2(j2, 4), B2_2_5 = MKB2(j2, 5), B2_2_6 = MKB2(j2, 6);

  // N-tile 24 fragments -> LDS (tids 0..63 emulate one wave's lanes; R8-verified)
  if (tid < 64) {
    int jj = 384 + n15;
    f16x8* BV1 = (f16x8*)BL1h;
    f16x8* BV2 = (f16x8*)BL2h;
    BV1[0 * 64 + tid] = MKB1(jj, 0); BV1[1 * 64 + tid] = MKB1(jj, 1);
    BV1[2 * 64 + tid] = MKB1(jj, 2); BV1[3 * 64 + tid] = MKB1(jj, 3);
    BV2[0 * 64 + tid] = MKB2(jj, 0); BV2[1 * 64 + tid] = MKB2(jj, 1);
    BV2[2 * 64 + tid] = MKB2(jj, 2); BV2[3 * 64 + tid] = MKB2(jj, 3);
    BV2[4 * 64 + tid] = MKB2(jj, 4); BV2[5 * 64 + tid] = MKB2(jj, 5);
    BV2[6 * 64 + tid] = MKB2(jj, 6);
  }

  // compact-A read offset: real lanes (m<2) read their 16B chunk; m>=2 lanes
  // read the tile's shared zero chunk (same-address broadcast, free)
  const int roff = (n15 < 2) ? (n15 * 32 + kg * 8) : 64;

  // ---------------- act duty: tids 256..455 -> (b, k) ----------------
  const int is_act = (tid >= 256 && tid < 256 + NB * HID);
  const int ab = (tid - 256) & 1;
  const int ak = (tid - 256) >> 1;
  float b1i = 0, b1f = 0, b1g = 0, b1o = 0, b2i = 0, b2f = 0, b2g = 0, b2o = 0;
  if (is_act) {
    b1i = bih1[ak] + bhh1[ak];             b1f = bih1[ak + 100] + bhh1[ak + 100];
    b1g = bih1[ak + 200] + bhh1[ak + 200]; b1o = bih1[ak + 300] + bhh1[ak + 300];
    b2i = bih2[ak] + bhh2[ak];             b2f = bih2[ak + 100] + bhh2[ak + 100];
    b2g = bih2[ak + 200] + bhh2[ak + 200]; b2o = bih2[ak + 300] + bhh2[ak + 300];
  }
  float c1v = 0.0f, c2v = 0.0f;

  // ---------------- y duty: tids 496..511 ----------------
  const int is_y = (tid >= 496);
  const int ybat = ((tid - 496) >> 3) & 1;
  const int yl = (tid - 496) & 7;
  const float blin0 = blin[0];

  __syncthreads();
  if (tid >= 464 && tid < 466) A1c[cidx(100, tid - 464)] = (__fp16)xrow[tid - 464][0];
  __syncthreads();

#define RDA(BUF, t) (*(const f16x8*)&(BUF)[(t) * 80 + roff])

  // held W3-partials (live across barriers B..D) + prefetched A1 frags
  f32x4 pA, pB, pC, p24;
  f16x8 pa0 = RDA(A1c, 0), pa1 = RDA(A1c, 1), pa2 = RDA(A1c, 2), pa3 = RDA(A1c, 3);

// G1: W1-chains over prefetched A1 frags  +  W3-part (frags 4..6 over h2 tiles 4..6,
// all-h2 tiles — h2(t-1) is valid here). Partials pA/pB/pC held in regs.
#define L1_PHASE { \
    f16x8 z4 = RDA(A2c, 4), z5 = RDA(A2c, 5), z6 = RDA(A2c, 6); \
    f32x4 c0 = {0.f,0.f,0.f,0.f}, c1 = {0.f,0.f,0.f,0.f}, c2 = {0.f,0.f,0.f,0.f}; \
    c0 = MF(pa0, B1_0_0, c0); c0 = MF(pa1, B1_0_1, c0); c0 = MF(pa2, B1_0_2, c0); c0 = MF(pa3, B1_0_3, c0); \
    c1 = MF(pa0, B1_1_0, c1); c1 = MF(pa1, B1_1_1, c1); c1 = MF(pa2, B1_1_2, c1); c1 = MF(pa3, B1_1_3, c1); \
    c2 = MF(pa0, B1_2_0, c2); c2 = MF(pa1, B1_2_1, c2); c2 = MF(pa2, B1_2_2, c2); c2 = MF(pa3, B1_2_3, c2); \
    pA = (f32x4){0.f,0.f,0.f,0.f}; pB = (f32x4){0.f,0.f,0.f,0.f}; pC = (f32x4){0.f,0.f,0.f,0.f}; \
    pA = MF(z4, B2_0_4, pA); pA = MF(z5, B2_0_5, pA); pA = MF(z6, B2_0_6, pA); \
    pB = MF(z4, B2_1_4, pB); pB = MF(z5, B2_1_5, pB); pB = MF(z6, B2_1_6, pB); \
    pC = MF(z4, B2_2_4, pC); pC = MF(z5, B2_2_5, pC); pC = MF(z6, B2_2_6, pC); \
    if (wv == 0) { \
      const f16x8* Bv1 = (const f16x8*)BL1h; \
      const f16x8* Bv2 = (const f16x8*)BL2h; \
      f32x4 c3 = {0.f,0.f,0.f,0.f}; \
      c3 = MF(pa0, Bv1[lane], c3); c3 = MF(pa1, Bv1[64 + lane], c3); \
      c3 = MF(pa2, Bv1[128 + lane], c3); c3 = MF(pa3, Bv1[192 + lane], c3); \
      p24 = (f32x4){0.f,0.f,0.f,0.f}; \
      p24 = MF(z4, Bv2[256 + lane], p24); p24 = MF(z5, Bv2[320 + lane], p24); \
      p24 = MF(z6, Bv2[384 + lane], p24); \
      if (lane < 16) gb2[384 + lane] = float2{c3[0], c3[1]}; \
    } \
    if (lane < 16) { \
      gb2[(wv << 4) + lane] = float2{c0[0], c0[1]}; \
      gb2[((8 + wv) << 4) + lane] = float2{c1[0], c1[1]}; \
      gb2[((16 + wv) << 4) + lane] = float2{c2[0], c2[1]}; \
    } }

// G2: frags 0..3 over tiles 0..3 (h1(t) k0..99 + h2(t-1) k112..127 — both valid
// here; ACT2 hasn't overwritten tile 3's h2-head yet). C-init = held partials.
#define L2_PHASE { \
    f16x8 n0 = RDA(A2c, 0), n1 = RDA(A2c, 1), n2 = RDA(A2c, 2), n3 = RDA(A2c, 3); \
    f32x4 d0 = pA, d1 = pB, d2 = pC; \
    d0 = MF(n0, B2_0_0, d0); d0 = MF(n1, B2_0_1, d0); d0 = MF(n2, B2_0_2, d0); d0 = MF(n3, B2_0_3, d0); \
    d1 = MF(n0, B2_1_0, d1); d1 = MF(n1, B2_1_1, d1); d1 = MF(n2, B2_1_2, d1); d1 = MF(n3, B2_1_3, d1); \
    d2 = MF(n0, B2_2_0, d2); d2 = MF(n1, B2_2_1, d2); d2 = MF(n2, B2_2_2, d2); d2 = MF(n3, B2_2_3, d2); \
    if (wv == 0) { \
      const f16x8* Bv2 = (const f16x8*)BL2h; \
      f32x4 d3 = p24; \
      d3 = MF(n0, Bv2[lane], d3); d3 = MF(n1, Bv2[64 + lane], d3); \
      d3 = MF(n2, Bv2[128 + lane], d3); d3 = MF(n3, Bv2[192 + lane], d3); \
      if (lane < 16) gb2[384 + lane] = float2{d3[0], d3[1]}; \
    } \
    if (lane < 16) { \
      gb2[(wv << 4) + lane] = float2{d0[0], d0[1]}; \
      gb2[((8 + wv) << 4) + lane] = float2{d1[0], d1[1]}; \
      gb2[((16 + wv) << 4) + lane] = float2{d2[0], d2[1]}; \
    } }

#define ACT1_BODY { \
    const float* gbf = (const float*)gb2; \
    float gi = gbf[(ak) * 2 + ab] + b1i; \
    float gf = gbf[(ak + 100) * 2 + ab] + b1f; \
    float gg = gbf[(ak + 200) * 2 + ab] + b1g; \
    float go = gbf[(ak + 300) * 2 + ab] + b1o; \
    c1v = sigm(gf) * c1v + sigm(gi) * tanh_fast(gg); \
    __fp16 h = (__fp16)(sigm(go) * tanh_fast(c1v)); \
    A1c[cidx(ak, ab)] = h; A2c[cidx(ak, ab)] = h; }

#define ACT2_BODY { \
    const float* gbf = (const float*)gb2; \
    float gi = gbf[(ak) * 2 + ab] + b2i; \
    float gf = gbf[(ak + 100) * 2 + ab] + b2f; \
    float gg = gbf[(ak + 200) * 2 + ab] + b2g; \
    float go = gbf[(ak + 300) * 2 + ab] + b2o; \
    c2v = sigm(gf) * c2v + sigm(gi) * tanh_fast(gg); \
    float hv = sigm(go) * tanh_fast(c2v); \
    A2c[cidx(112 + ak, ab)] = (__fp16)hv; ybuf[ab][ak] = hv; }

#define Y_BODY(tt, FEED) { \
    float s = 0.0f; \
    _Pragma("unroll") \
    for (int m = 0; m < 13; m++) s = fmaf(ybuf[ybat][yl + 8 * m], wls[yl + 8 * m], s); \
    s += __shfl_down(s, 4, 8); \
    s += __shfl_down(s, 2, 8); \
    s += __shfl_down(s, 1, 8); \
    if (yl == 0) { \
      float y = s + blin0; \
      out[(size_t)(b0 + ybat) * TT + (tt)] = y; \
      if (FEED) A1c[cidx(100, ybat)] = (__fp16)y; \
    } }

  // ================= teacher-forced: 4 barriers/step =================
  for (int t = 0; t < T_IN; t++) {
    __syncthreads();  // A: h2(t-1) visible; gb2 free; prefetched pa* valid
    L1_PHASE
    if (is_y && t > 0) Y_BODY(t - 1, 0)   // y(t-1) off critical path
    __syncthreads();  // B: gb2 (L1) ready
    if (is_act) ACT1_BODY
    if (tid >= 464 && tid < 466 && t + 1 < T_IN)
      A1c[cidx(100, tid - 464)] = (__fp16)xrow[tid - 464][t + 1];
    __syncthreads();  // C: h1(t) visible; gb2 free
    L2_PHASE
    __syncthreads();  // D: gb2 (L2) ready
    if (is_act) ACT2_BODY
    // prefetch next step's A1 frags (h1(t)+x(t+1), stable since barrier C) —
    // overlaps the ACT2 window, removes LDS latency from phase A
    pa0 = RDA(A1c, 0); pa1 = RDA(A1c, 1); pa2 = RDA(A1c, 2); pa3 = RDA(A1c, 3);
  }

  // ================= autoregressive: 5 barriers/step =================
  for (int t = T_IN; t < TT; t++) {
    __syncthreads();  // ybuf(t-1) ready
    if (is_y) Y_BODY(t - 1, 1)            // y(t-1) -> out + x(t) feed into A1
    __syncthreads();  // A1 x ready
    pa0 = RDA(A1c, 0); pa1 = RDA(A1c, 1); pa2 = RDA(A1c, 2); pa3 = RDA(A1c, 3);
    L1_PHASE
    __syncthreads();
    if (is_act) ACT1_BODY
    __syncthreads();
    L2_PHASE
    __syncthreads();
    if (is_act) ACT2_BODY
  }
  __syncthreads();
  if (is_y) Y_BODY(TT - 1, 0)             // final y
}

extern "C" void kernel_launch(void* const* d_in, const int* in_sizes, int n_in,
                              void* d_out, int out_size, void* d_ws, size_t ws_size,
                              hipStream_t stream) {
  const float* input = (const float*)d_in[0];
  const float* Wih1  = (const float*)d_in[1];
  const float* Whh1  = (const float*)d_in[2];
  const float* bih1  = (const float*)d_in[3];
  const float* bhh1  = (const float*)d_in[4];
  const float* Wih2  = (const float*)d_in[5];
  const float* Whh2  = (const float*)d_in[6];
  const float* bih2  = (const float*)d_in[7];
  const float* bhh2  = (const float*)d_in[8];
  const float* Wlin  = (const float*)d_in[9];
  const float* blin  = (const float*)d_in[10];
  const int*   futp  = (const int*)d_in[11];
  float* out = (float*)d_out;

  dim3 grid(B_TOTAL / NB);  // 256 blocks, 1 per CU
  dim3 block(BLOCK);
  hipLaunchKernelGGL(lstm2_mfma, grid, block, 0, stream,
                     input, Wih1, Whh1, bih1, bhh1, Wih2, Whh2, bih2, bhh2,
                     Wlin, blin, futp, out);
}